// Round 24
// baseline (41.790 us; speedup 1.0000x reference)
//
#include <hip/hip_runtime.h>
#include <hip/hip_bf16.h>
#include <math.h>

#define BS 8192
#define D 128
#define NROWS 16384               // 2*BS
#define COLS_PER_BLOCK 512
#define NCHUNK (COLS_PER_BLOCK / 16)      // 32 col-chunks of 16
#define NSPLIT (NROWS / COLS_PER_BLOCK)   // 32 col-splits
#define NPART NSPLIT                      // 32 partial buffers

typedef int i32x4 __attribute__((ext_vector_type(4)));
typedef int i32x8 __attribute__((ext_vector_type(8)));
typedef float f32x4 __attribute__((ext_vector_type(4)));

#define LN2F 0.6931471805599453f
// store scale: elements written as x * 2^4 * sqrt(log2e) / ||row||; HW E8M0
// scale 2^-4 on A and B restores acc = sim * log2e exactly (powers of 2).
#define STORE_SCALE 19.217958569050494f   // 16 * 1.2011224087864498
#define E8M0_M4 123                       // 2^(123-127) = 2^-4
#define FMT_FP4 4                         // cbsz/blgp format code for e2m1

// Taylor coefficients of 2^x: c_k = (ln2)^k / k!  (|x|<=1.6 -> err ~6e-5)
#define PC1 0.69314718056f
#define PC2 0.24022650696f
#define PC3 0.05550410866f
#define PC4 0.00961812911f
#define PC5 0.00133335581f
#define PC6 1.54035304e-4f
#define PC7 1.52527338e-5f

#if __has_builtin(__builtin_amdgcn_exp2f)
#define EXP2F(x) __builtin_amdgcn_exp2f(x)
#else
#define EXP2F(x) exp2f(x)
#endif

// Layout of catF (fp4, "16-row-group tiled"): cell = 16 rows x K=128 fp4 =
// 1024 B contiguous. Byte addr of (row, k): (row>>4)*1024 + (k>>5)*256 +
// (row&15)*16 + (k&31)/2 ; even k = LOW nibble, odd k = HIGH nibble.

// Kernel 1: row norms + scaled fp4(e2m1) conversion into catF.
// e2m1 code by 7-threshold count: codes 0..7 = {0,.5,1,1.5,2,3,4,6}.
// Also re-zeroes the finalize completion counter (graph-replay safe).
__global__ __launch_bounds__(256) void nrm_cvt(const float* __restrict__ f,
                                               const float* __restrict__ noise,
                                               char* __restrict__ catF,
                                               unsigned int* __restrict__ cnt) {
  if (blockIdx.x == 0 && threadIdx.x == 0) cnt[0] = 0;
  const int lane = threadIdx.x & 63;
  const int wv = threadIdx.x >> 6;
  const int row = blockIdx.x * 4 + wv;
  const float* src = (row < BS) ? (noise + (size_t)row * D) : (f + (size_t)(row - BS) * D);
  float2 v = ((const float2*)src)[lane];   // k = 2*lane, 2*lane+1 (same byte)
  float ss = v.x * v.x + v.y * v.y;
#pragma unroll
  for (int m = 1; m <= 32; m <<= 1) ss += __shfl_xor(ss, m, 64);
  const float s = STORE_SCALE / sqrtf(ss);
  auto q4 = [](float x) {
    const float av = fabsf(x);
    int c = (av > 0.25f) + (av > 0.75f) + (av > 1.25f) + (av > 1.75f) +
            (av > 2.5f) + (av > 3.5f) + (av > 5.0f);
    return c | ((x < 0.f) ? 8 : 0);
  };
  const int b = q4(v.x * s) | (q4(v.y * s) << 4);  // even k low nibble
  const int b1 = __shfl_down(b, 1, 64);
  const int b2 = __shfl_down(b, 2, 64);
  const int b3 = __shfl_down(b, 3, 64);
  if ((lane & 3) == 0) {
    const unsigned word = (unsigned)b | ((unsigned)b1 << 8) |
                          ((unsigned)b2 << 16) | ((unsigned)b3 << 24);
    char* dst = catF + ((size_t)(row >> 4) << 10) + ((lane >> 4) << 8) +
                ((row & 15) << 4) + (lane & 15);
    *(unsigned*)dst = word;
  }
}

__device__ __forceinline__ i32x8 mk8(i32x4 v) {
  i32x8 r = {v[0], v[1], v[2], v[3], 0, 0, 0, 0};
  return r;
}

// scalar degree-7 Taylor of 2^x - 1 (compiler emits full-rate v_fmac chains)
__device__ __forceinline__ float p2m1(float x) {
  float q = PC7;
  q = q * x + PC6; q = q * x + PC5; q = q * x + PC4;
  q = q * x + PC3; q = q * x + PC2; q = q * x + PC1;
  return q * x;
}

// Kernel 2: fused GEMM + PIPE-BALANCED exp + row-sum, MX-FP4 K=128, acc
// double-buffer. R19/R21 measurement: the 13.6us exp marginal == v_exp_f32
// throughput (16 cyc/wave64) on the shared per-SIMD trans pipe, while the
// VALU idles. Here each chunk routes rf=0,1 through v_exp (trans pipe) and
// rf=2,3 through a scalar Taylor poly accumulating 2^x - 1 (VALU, full-rate
// fmac; +32 count correction at the end; diagonal exclusions contribute -1).
// Both pipes get ~7us of work; a wave's trans issue (1cyc) leaves slots to
// feed the VALU stream -> epilogue ~ max(pipes) instead of trans-serial.
__global__ __launch_bounds__(256) void infonce_main(
    const char* __restrict__ catF,
    float* __restrict__ ws_neg, float* __restrict__ ws_pos) {
  const int tid = threadIdx.x;
  const int lane = tid & 63;
  const int w = tid >> 6;
  const int l15 = lane & 15, l4 = lane >> 4;
  const int nb = blockIdx.x, mb = blockIdx.y;
  const int growbase = mb * 256 + w * 64;
  const int col0 = nb * COLS_PER_BLOCK;
  const int lbase = l4 * 256 + l15 * 16;

  // A fragments: 64 f-rows x K=128 fp4 (data in low 4 regs of each operand)
  i32x8 a[4];
  {
    const char* ab = catF + ((size_t)((BS + growbase) >> 4) << 10) + lbase;
#pragma unroll
    for (int rf = 0; rf < 4; rf++) a[rf] = mk8(*(const i32x4*)(ab + rf * 1024));
  }

  f32x4 rs[4];
  const f32x4 z = {0.f, 0.f, 0.f, 0.f};
#pragma unroll
  for (int rf = 0; rf < 4; rf++) rs[rf] = z;

  const char* bl = catF + ((size_t)(col0 >> 4) << 10) + lbase;

  auto ld = [&](int c) { return mk8(*(const i32x4*)(bl + (size_t)c * 1024)); };

  auto domfma = [&](f32x4* acc, const i32x8& b) {
#pragma unroll
    for (int rf = 0; rf < 4; rf++)
      acc[rf] = __builtin_amdgcn_mfma_scale_f32_16x16x128_f8f6f4(
          a[rf], b, z, FMT_FP4, FMT_FP4, 0, E8M0_M4, 0, E8M0_M4);
  };

  auto epi = [&](const f32x4* acc, int c) {
    const int c0 = col0 + c * 16;
    const bool dPos = ((c0 & ~63) == growbase);          // cols == f-row ids
    const bool dSelf = (((c0 - BS) & ~63) == growbase);  // cols == i+bs
    if (!dPos && !dSelf) {
      // trans-pipe half: rf 0,1 via v_exp
#pragma unroll
      for (int rf = 0; rf < 2; rf++) {
        f32x4 e;
#pragma unroll
        for (int r = 0; r < 4; r++) e[r] = EXP2F(acc[rf][r]);
        rs[rf] += e;
      }
      // VALU half: rf 2,3 via Taylor (accumulates 2^x - 1)
#pragma unroll
      for (int rf = 2; rf < 4; rf++)
#pragma unroll
        for (int r = 0; r < 4; r++) rs[rf][r] += p2m1(acc[rf][r]);
    } else {
#pragma unroll
      for (int rf = 0; rf < 4; rf++)
#pragma unroll
        for (int r = 0; r < 4; r++) {
          const int grow = growbase + rf * 16 + l4 * 4 + r;
          const int gcol = c0 + l15;
          const float v = acc[rf][r];
          const bool ex = dPos ? (gcol == grow) : (gcol == grow + BS);
          if (dPos && gcol == grow) ws_pos[grow] = v;  // sim_pos * log2e
          if (rf < 2) rs[rf][r] += ex ? 0.f : EXP2F(v);
          else        rs[rf][r] += ex ? -1.f : (EXP2F(v) - 1.f);
        }
    }
  };

  // 4-slot B ring, loads 2 chunks ahead of their MFMA.
  i32x8 bb[4];
  bb[0] = ld(0);
  bb[1] = ld(1);

  f32x4 accA[4], accB[4];
  domfma(accA, bb[0]);   // chunk 0
  bb[2] = ld(2);
  domfma(accB, bb[1]);   // chunk 1
  bb[3] = ld(3);

#pragma unroll
  for (int ph = 0; ph < 15; ++ph) {
    const int c = 2 * ph;  // accA=chunk c (pending epi), accB=chunk c+1
    __builtin_amdgcn_sched_barrier(0);
    epi(accA, c);                          // covers accB's MFMA in flight
    if (c + 4 < NCHUNK) bb[(c + 4) & 3] = ld(c + 4);
    domfma(accA, bb[(c + 2) & 3]);         // chunk c+2
    __builtin_amdgcn_sched_barrier(0);
    epi(accB, c + 1);                      // covers accA's MFMA in flight
    if (c + 5 < NCHUNK) bb[(c + 5) & 3] = ld(c + 5);
    domfma(accB, bb[(c + 3) & 3]);         // chunk c+3
  }
  __builtin_amdgcn_sched_barrier(0);
  epi(accA, NCHUNK - 2);
  epi(accB, NCHUNK - 1);

  // poly half accumulated 2^x - 1: add back 32 (one per chunk) per slot
  rs[2] += (f32x4){32.f, 32.f, 32.f, 32.f};
  rs[3] += (f32x4){32.f, 32.f, 32.f, 32.f};

  // reduce rowsums across the 16 lanes (l15) sharing each row
  float rowsum[16];
#pragma unroll
  for (int rf = 0; rf < 4; rf++)
#pragma unroll
    for (int r = 0; r < 4; r++) {
      float v = rs[rf][r];
      v += __shfl_xor(v, 1, 64);
      v += __shfl_xor(v, 2, 64);
      v += __shfl_xor(v, 4, 64);
      v += __shfl_xor(v, 8, 64);
      rowsum[rf * 4 + r] = v;
    }
  if (l15 == 0) {
    float* dst = ws_neg + (size_t)nb * BS + growbase;
#pragma unroll
    for (int rf = 0; rf < 4; rf++)
#pragma unroll
      for (int r = 0; r < 4; r++) dst[rf * 16 + l4 * 4 + r] = rowsum[rf * 4 + r];
  }
}

// Kernel 3: per-row loss + mean, single kernel (last-block-done tail).
__global__ __launch_bounds__(256) void finalize(const float* __restrict__ ws_neg,
                                                const float* __restrict__ ws_pos,
                                                float* __restrict__ partial,
                                                unsigned int* __restrict__ cnt,
                                                float* __restrict__ out) {
  __shared__ float red[4];
  __shared__ int flag;
  const int tid = threadIdx.x;
  const int lane = tid & 63;
  const int w = tid >> 6;
  const int row = blockIdx.x * 256 + tid;
  float neg = 0.f;
#pragma unroll
  for (int p = 0; p < NPART; p++) neg += ws_neg[(size_t)p * BS + row];
  // loss = log(neg_sum + eps) - sim_pos ; sim_pos = (sim*log2e)*ln2
  float local = logf(neg + 1e-6f) - ws_pos[row] * LN2F;
#pragma unroll
  for (int m = 1; m <= 32; m <<= 1) local += __shfl_xor(local, m, 64);
  if (lane == 0) red[w] = local;
  __syncthreads();
  if (tid == 0) {
    partial[blockIdx.x] = red[0] + red[1] + red[2] + red[3];
    __threadfence();  // release: partial visible before the bump
    flag = (atomicAdd(cnt, 1u) == (unsigned)(BS / 256 - 1));
  }
  __syncthreads();
  if (!flag) return;
  __threadfence();    // acquire: see all blocks' partials
  if (tid < 64) {
    float v = (tid < 32) ? partial[tid] : 0.f;
#pragma unroll
    for (int m = 1; m <= 32; m <<= 1) v += __shfl_xor(v, m, 64);
    if (tid == 0) out[0] = v * (1.f / BS);
  }
}

extern "C" void kernel_launch(void* const* d_in, const int* in_sizes, int n_in,
                              void* d_out, int out_size, void* d_ws, size_t ws_size,
                              hipStream_t stream) {
  const float* f = (const float*)d_in[0];
  const float* noise = (const float*)d_in[1];
  char* ws = (char*)d_ws;
  char* catF = ws;                                       // 1 MiB (fp4 tiled)
  float* ws_pos = (float*)(ws + (size_t)NROWS * 64);     // 32 KiB
  float* ws_neg = ws_pos + BS;                           // 1 MiB
  float* partial = ws_neg + (size_t)NPART * BS;          // 128 B
  unsigned int* cnt = (unsigned int*)(partial + 32);

  nrm_cvt<<<NROWS / 4, 256, 0, stream>>>(f, noise, catF, cnt);
  dim3 grid(NSPLIT, BS / 256);                           // 32 x 32 = 1024 blocks
  infonce_main<<<grid, 256, 0, stream>>>(catF, ws_neg, ws_pos);
  finalize<<<BS / 256, 256, 0, stream>>>(ws_neg, ws_pos, partial, cnt, (float*)d_out);
}

// Round 25
// 36.110 us; speedup vs baseline: 1.1573x; 1.1573x over previous
//
#include <hip/hip_runtime.h>
#include <hip/hip_bf16.h>
#include <math.h>

#define BS 8192
#define D 128
#define NROWS 16384               // 2*BS
#define COLS_PER_BLOCK 512
#define NCHUNK (COLS_PER_BLOCK / 16)      // 32 col-chunks of 16
#define NSPLIT (NROWS / COLS_PER_BLOCK)   // 32 col-splits
#define NPART NSPLIT                      // 32 partial buffers

typedef int i32x4 __attribute__((ext_vector_type(4)));
typedef int i32x8 __attribute__((ext_vector_type(8)));
typedef float f32x4 __attribute__((ext_vector_type(4)));

#define LN2F 0.6931471805599453f
// store scale: elements written as x * 2^4 * sqrt(log2e) / ||row||; HW E8M0
// scale 2^-4 on A and B restores acc = sim * log2e exactly (powers of 2).
// For fp4(e2m1): max stored |x| ~ 0.31*19.2 = 5.95 <= 6 (fp4 max) — fits.
#define STORE_SCALE 19.217958569050494f   // 16 * 1.2011224087864498
#define E8M0_M4 123                       // 2^(123-127) = 2^-4
#define FMT_FP4 4                         // cbsz/blgp format code for e2m1

#if __has_builtin(__builtin_amdgcn_exp2f)
#define EXP2F(x) __builtin_amdgcn_exp2f(x)
#else
#define EXP2F(x) exp2f(x)
#endif

// Layout of catF (fp4, "16-row-group tiled"): cell = 16 rows x K=128 fp4 =
// 1024 B contiguous. Byte addr of (row, k): (row>>4)*1024 + (k>>5)*256 +
// (row&15)*16 + (k&31)/2 ; even k = LOW nibble, odd k = HIGH nibble.
// An MFMA fragment (lanes: l15=row/col, l4=k-block-of-32) is lane 16B at
// l4*256 + l15*16 — the wave's 64x16B = the whole 1 KiB cell, coalesced.

// Kernel 1: row norms + scaled fp4(e2m1) conversion into catF.
// e2m1 code by 7-threshold count: codes 0..7 = {0,.5,1,1.5,2,3,4,6}.
// Also re-zeroes the finalize completion counter (graph-replay safe).
__global__ __launch_bounds__(256) void nrm_cvt(const float* __restrict__ f,
                                               const float* __restrict__ noise,
                                               char* __restrict__ catF,
                                               unsigned int* __restrict__ cnt) {
  if (blockIdx.x == 0 && threadIdx.x == 0) cnt[0] = 0;
  const int lane = threadIdx.x & 63;
  const int wv = threadIdx.x >> 6;
  const int row = blockIdx.x * 4 + wv;
  const float* src = (row < BS) ? (noise + (size_t)row * D) : (f + (size_t)(row - BS) * D);
  float2 v = ((const float2*)src)[lane];   // k = 2*lane, 2*lane+1 (same byte)
  float ss = v.x * v.x + v.y * v.y;
#pragma unroll
  for (int m = 1; m <= 32; m <<= 1) ss += __shfl_xor(ss, m, 64);
  const float s = STORE_SCALE / sqrtf(ss);
  auto q4 = [](float x) {
    const float av = fabsf(x);
    int c = (av > 0.25f) + (av > 0.75f) + (av > 1.25f) + (av > 1.75f) +
            (av > 2.5f) + (av > 3.5f) + (av > 5.0f);
    return c | ((x < 0.f) ? 8 : 0);
  };
  const int b = q4(v.x * s) | (q4(v.y * s) << 4);  // even k low nibble
  const int b1 = __shfl_down(b, 1, 64);
  const int b2 = __shfl_down(b, 2, 64);
  const int b3 = __shfl_down(b, 3, 64);
  if ((lane & 3) == 0) {
    const unsigned word = (unsigned)b | ((unsigned)b1 << 8) |
                          ((unsigned)b2 << 16) | ((unsigned)b3 << 24);
    char* dst = catF + ((size_t)(row >> 4) << 10) + ((lane >> 4) << 8) +
                ((row & 15) << 4) + (lane & 15);
    *(unsigned*)dst = word;
  }
}

__device__ __forceinline__ i32x8 mk8(i32x4 v) {
  i32x8 r = {v[0], v[1], v[2], v[3], 0, 0, 0, 0};
  return r;
}

// Kernel 2 (R21 verbatim — best measured, 36.1 us total, reproduced twice):
// fused GEMM + exp2 + row-sum, MX-FP4 K=128, acc double-buffer. Measured
// model (R19 ablation): main = floor(8us: MFMA+loads+scaffold) + exp(13.6us,
// v_exp_f32 trans-pipe throughput for 134M ops) + adds(5us), additive per
// wave. Work-removal moved this wall 3/3 times (fp8 -12us, fp4 -4.2us);
// all 9 scheduling levers null; triangle symmetry refuted twice (R12, R22);
// poly-exp substitution refuted thrice (R15, R24).
__global__ __launch_bounds__(256) void infonce_main(
    const char* __restrict__ catF,
    float* __restrict__ ws_neg, float* __restrict__ ws_pos) {
  const int tid = threadIdx.x;
  const int lane = tid & 63;
  const int w = tid >> 6;
  const int l15 = lane & 15, l4 = lane >> 4;
  const int nb = blockIdx.x, mb = blockIdx.y;
  const int growbase = mb * 256 + w * 64;
  const int col0 = nb * COLS_PER_BLOCK;
  const int lbase = l4 * 256 + l15 * 16;

  // A fragments: 64 f-rows x K=128 fp4 (data in low 4 regs of each operand)
  i32x8 a[4];
  {
    const char* ab = catF + ((size_t)((BS + growbase) >> 4) << 10) + lbase;
#pragma unroll
    for (int rf = 0; rf < 4; rf++) a[rf] = mk8(*(const i32x4*)(ab + rf * 1024));
  }

  f32x4 rs[4];
  const f32x4 z = {0.f, 0.f, 0.f, 0.f};
#pragma unroll
  for (int rf = 0; rf < 4; rf++) rs[rf] = z;

  const char* bl = catF + ((size_t)(col0 >> 4) << 10) + lbase;

  auto ld = [&](int c) { return mk8(*(const i32x4*)(bl + (size_t)c * 1024)); };

  auto domfma = [&](f32x4* acc, const i32x8& b) {
#pragma unroll
    for (int rf = 0; rf < 4; rf++)
      acc[rf] = __builtin_amdgcn_mfma_scale_f32_16x16x128_f8f6f4(
          a[rf], b, z, FMT_FP4, FMT_FP4, 0, E8M0_M4, 0, E8M0_M4);
  };

  auto epi = [&](const f32x4* acc, int c) {
    const int c0 = col0 + c * 16;
    const bool dPos = ((c0 & ~63) == growbase);          // cols == f-row ids
    const bool dSelf = (((c0 - BS) & ~63) == growbase);  // cols == i+bs
    if (!dPos && !dSelf) {
#pragma unroll
      for (int rf = 0; rf < 4; rf++) {
        f32x4 e;
#pragma unroll
        for (int r = 0; r < 4; r++) e[r] = EXP2F(acc[rf][r]);
        rs[rf] += e;
      }
    } else {
#pragma unroll
      for (int rf = 0; rf < 4; rf++)
#pragma unroll
        for (int r = 0; r < 4; r++) {
          const int grow = growbase + rf * 16 + l4 * 4 + r;
          const int gcol = c0 + l15;
          const float v = acc[rf][r];
          const bool ex = dPos ? (gcol == grow) : (gcol == grow + BS);
          if (dPos && gcol == grow) ws_pos[grow] = v;  // sim_pos * log2e
          rs[rf][r] += ex ? 0.f : EXP2F(v);
        }
    }
  };

  // 4-slot B ring, loads 2 chunks ahead of their MFMA.
  i32x8 bb[4];
  bb[0] = ld(0);
  bb[1] = ld(1);

  f32x4 accA[4], accB[4];
  domfma(accA, bb[0]);   // chunk 0
  bb[2] = ld(2);
  domfma(accB, bb[1]);   // chunk 1
  bb[3] = ld(3);

#pragma unroll
  for (int ph = 0; ph < 15; ++ph) {
    const int c = 2 * ph;  // accA=chunk c (pending epi), accB=chunk c+1
    __builtin_amdgcn_sched_barrier(0);
    epi(accA, c);                          // covers accB's MFMA in flight
    if (c + 4 < NCHUNK) bb[(c + 4) & 3] = ld(c + 4);
    domfma(accA, bb[(c + 2) & 3]);         // chunk c+2
    __builtin_amdgcn_sched_barrier(0);
    epi(accB, c + 1);                      // covers accA's MFMA in flight
    if (c + 5 < NCHUNK) bb[(c + 5) & 3] = ld(c + 5);
    domfma(accB, bb[(c + 3) & 3]);         // chunk c+3
  }
  __builtin_amdgcn_sched_barrier(0);
  epi(accA, NCHUNK - 2);
  epi(accB, NCHUNK - 1);

  // reduce rowsums across the 16 lanes (l15) sharing each row
  float rowsum[16];
#pragma unroll
  for (int rf = 0; rf < 4; rf++)
#pragma unroll
    for (int r = 0; r < 4; r++) {
      float v = rs[rf][r];
      v += __shfl_xor(v, 1, 64);
      v += __shfl_xor(v, 2, 64);
      v += __shfl_xor(v, 4, 64);
      v += __shfl_xor(v, 8, 64);
      rowsum[rf * 4 + r] = v;
    }
  if (l15 == 0) {
    float* dst = ws_neg + (size_t)nb * BS + growbase;
#pragma unroll
    for (int rf = 0; rf < 4; rf++)
#pragma unroll
      for (int r = 0; r < 4; r++) dst[rf * 16 + l4 * 4 + r] = rowsum[rf * 4 + r];
  }
}

// Kernel 3: per-row loss + mean, single kernel (last-block-done tail).
__global__ __launch_bounds__(256) void finalize(const float* __restrict__ ws_neg,
                                                const float* __restrict__ ws_pos,
                                                float* __restrict__ partial,
                                                unsigned int* __restrict__ cnt,
                                                float* __restrict__ out) {
  __shared__ float red[4];
  __shared__ int flag;
  const int tid = threadIdx.x;
  const int lane = tid & 63;
  const int w = tid >> 6;
  const int row = blockIdx.x * 256 + tid;
  float neg = 0.f;
#pragma unroll
  for (int p = 0; p < NPART; p++) neg += ws_neg[(size_t)p * BS + row];
  // loss = log(neg_sum + eps) - sim_pos ; sim_pos = (sim*log2e)*ln2
  float local = logf(neg + 1e-6f) - ws_pos[row] * LN2F;
#pragma unroll
  for (int m = 1; m <= 32; m <<= 1) local += __shfl_xor(local, m, 64);
  if (lane == 0) red[w] = local;
  __syncthreads();
  if (tid == 0) {
    partial[blockIdx.x] = red[0] + red[1] + red[2] + red[3];
    __threadfence();  // release: partial visible before the bump
    flag = (atomicAdd(cnt, 1u) == (unsigned)(BS / 256 - 1));
  }
  __syncthreads();
  if (!flag) return;
  __threadfence();    // acquire: see all blocks' partials
  if (tid < 64) {
    float v = (tid < 32) ? partial[tid] : 0.f;
#pragma unroll
    for (int m = 1; m <= 32; m <<= 1) v += __shfl_xor(v, m, 64);
    if (tid == 0) out[0] = v * (1.f / BS);
  }
}

extern "C" void kernel_launch(void* const* d_in, const int* in_sizes, int n_in,
                              void* d_out, int out_size, void* d_ws, size_t ws_size,
                              hipStream_t stream) {
  const float* f = (const float*)d_in[0];
  const float* noise = (const float*)d_in[1];
  char* ws = (char*)d_ws;
  char* catF = ws;                                       // 1 MiB (fp4 tiled)
  float* ws_pos = (float*)(ws + (size_t)NROWS * 64);     // 32 KiB
  float* ws_neg = ws_pos + BS;                           // 1 MiB
  float* partial = ws_neg + (size_t)NPART * BS;          // 128 B
  unsigned int* cnt = (unsigned int*)(partial + 32);

  nrm_cvt<<<NROWS / 4, 256, 0, stream>>>(f, noise, catF, cnt);
  dim3 grid(NSPLIT, BS / 256);                           // 32 x 32 = 1024 blocks
  infonce_main<<<grid, 256, 0, stream>>>(catF, ws_neg, ws_pos);
  finalize<<<BS / 256, 256, 0, stream>>>(ws_neg, ws_pos, partial, cnt, (float*)d_out);
}